// Round 2
// baseline (235.361 us; speedup 1.0000x reference)
//
#include <hip/hip_runtime.h>
#include <hip/hip_fp16.h>
#include <math.h>

// FrFT (Ozaktas, 0.5<a<1.5): x[256,4096] f32, order f32 -> Re(complex64) f32
// out[b*4096+j]. R15: full-K per wave, zero atomics, 2 kernels total.
//
//   s1_full: xiT[b,s] = sum_i x[b,i]*w1(s-i)   (K=4096, f16 plain store to ws)
//   s2_full: out[b,j] = scale * [ sum_i x[b,i]*cos(ph(j,2i))
//                               + sum_i xiT[b,i]*cos(ph(j,2i+1)) ]
//            both segments accumulated in-register, single f32 store.
//
// Geometry (both stages): wave tile 32x32 (2x2 MFMA frags), block = 4 waves
// (64x64 tile), grid 256 blocks = 1 block/CU. XCD swizzle: blocks sharing the
// same 64 b-rows land on one XCD pair -> x slice (1MB) + xiT slice (0.5MB)
// stay L2-resident.
//
// Weight phase per 8-wide fragment is an exact quadratic in e:
//   ph(e) = P0 + e*(P1 + e*P2), P2 = 4(c-q), P1 = -4(q*k0 + c*d0),
//   P0 from exact int squares (same rounding as proven direct form).
// MFMA operand conventions identical to the R14-proven kernel.

#define NN 4096
#define BB 256
#define KK (2*NN - 1)

typedef unsigned int uint;
typedef __attribute__((ext_vector_type(4))) float f32x4;
typedef __attribute__((ext_vector_type(8))) _Float16 half8;

struct LitConsts { float c, q, scale, pe; };

__device__ __forceinline__ LitConsts get_lit(const float* order) {
  float a = order[0];
  float alpha = a * (float)M_PI * 0.5f;
  float sina = sinf(alpha);
  float tana2 = tanf(alpha * 0.5f);
  LitConsts L;
  L.c = (float)M_PI / (float)NN / sina / 4.0f;
  L.q = ((float)M_PI / (float)NN) * (tana2 * 0.25f);
  L.scale = sqrtf(L.c / (float)M_PI);
  L.pe = -(1.0f - a) * (float)M_PI * 0.25f;
  return L;
}

__device__ __forceinline__ float xload(const float* __restrict__ x, uint idx, uint cap) {
  return (idx < cap) ? x[idx] : 0.f;
}

// XCD-aware block remap for grid (64 x-tiles, 4 y-tiles) flattened to 256.
// All 32 blocks on one XCD share the same y (same 64 b-rows).
__device__ __forceinline__ void swz_bxby(int id, int& bx, int& by) {
  int xcd = id & 7, grp = id >> 3;
  by = xcd >> 1;                 // 0..3
  bx = (xcd & 1) | (grp << 1);   // 0..63
}

// ---- stage 1: full-K sinc interp, plain f16 stores, no atomics ----
__global__ __launch_bounds__(256) void s1_full(const float* __restrict__ x,
                                               _Float16* __restrict__ xiT) {
  int bx, by; swz_bxby(blockIdx.x, bx, by);
  const int lane = threadIdx.x & 63, wave = threadIdx.x >> 6;
  const int l15 = lane & 15, lhi = lane >> 4;
  const int b0 = by * 64 + (wave >> 1) * 32;
  const int s0 = bx * 64 + (wave & 1) * 32;
  const float C2PI = 0.63661977236758134f;

  f32x4 acc[2][2] = {};  // [fm(b)][fs(s)]

#pragma unroll 2
  for (int st = 0; st < 128; ++st) {
    const int i0 = st * 32 + lhi * 8;
    half8 a[2];
#pragma unroll
    for (int fm = 0; fm < 2; ++fm) {
      const float* px = x + (size_t)(b0 + fm * 16 + l15) * NN + i0;
      f32x4 u0 = *(const f32x4*)px;
      f32x4 u1 = *(const f32x4*)(px + 4);
      half8 h;
#pragma unroll
      for (int e = 0; e < 4; ++e) { h[e] = (_Float16)u0[e]; h[e + 4] = (_Float16)u1[e]; }
      a[fm] = h;
    }
#pragma unroll
    for (int fs = 0; fs < 2; ++fs) {
      const int sl = s0 + fs * 16 + l15;
      const int t0 = sl - i0;
      const int den0 = 2 * t0 + 1;
      half8 bh;
#pragma unroll
      for (int e = 0; e < 8; ++e) {
        const float num = ((t0 ^ e) & 1) ? -C2PI : C2PI;
        bh[e] = (_Float16)__fdividef(num, (float)(den0 - 2 * e));
      }
#pragma unroll
      for (int fm = 0; fm < 2; ++fm)
        acc[fm][fs] = __builtin_amdgcn_mfma_f32_16x16x32_f16(a[fm], bh, acc[fm][fs], 0, 0, 0);
    }
  }
#pragma unroll
  for (int fm = 0; fm < 2; ++fm) {
    const int br = b0 + fm * 16 + lhi * 4;
#pragma unroll
    for (int fs = 0; fs < 2; ++fs) {
      const int sl = s0 + fs * 16 + l15;
#pragma unroll
      for (int rr = 0; rr < 4; ++rr)
        xiT[(size_t)(br + rr) * NN + sl] = (_Float16)acc[fm][fs][rr];
    }
  }
}

// ---- stage 2 segment: accumulate one parity of r over full K ----
template <int ODD>
__device__ __forceinline__ void s2_seg(const float* __restrict__ x,
                                       const _Float16* __restrict__ xiT,
                                       const LitConsts& L,
                                       const float* jbase, const int* jl,
                                       int b0, int l15, int lhi,
                                       f32x4 acc[2][2]) {
  const float P2 = 4.f * (L.c - L.q);
#pragma unroll 2
  for (int st = 0; st < 128; ++st) {
    const int i0 = st * 32 + lhi * 8;
    half8 a[2];
    if (ODD) {
#pragma unroll
      for (int fm = 0; fm < 2; ++fm)
        a[fm] = *(const half8*)(xiT + (size_t)(b0 + fm * 16 + l15) * NN + i0);
    } else {
#pragma unroll
      for (int fm = 0; fm < 2; ++fm) {
        const float* px = x + (size_t)(b0 + fm * 16 + l15) * NN + i0;
        f32x4 u0 = *(const f32x4*)px;
        f32x4 u1 = *(const f32x4*)(px + 4);
        half8 h;
#pragma unroll
        for (int e = 0; e < 4; ++e) { h[e] = (_Float16)u0[e]; h[e + 4] = (_Float16)u1[e]; }
        a[fm] = h;
      }
    }
    const int r0 = 2 * i0 + ODD;
    const int k0 = r0 - (NN - 1);
    const float bk = -L.q * (float)(k0 * k0);
    const float qk0 = L.q * (float)k0;
#pragma unroll
    for (int fj = 0; fj < 2; ++fj) {
      const int d0 = 2 * jl[fj] - r0;
      const float P0 = fmaf(L.c, (float)(d0 * d0), jbase[fj] + bk);
      const float P1 = -4.f * fmaf(L.c, (float)d0, qk0);
      half8 bh;
#pragma unroll
      for (int e = 0; e < 8; ++e) {
        const float ef = (float)e;
        float ph = fmaf(ef, fmaf(ef, P2, P1), P0);
        float w = __cosf(ph);
        if (ODD && (i0 + e) > (NN - 2)) w = 0.f;  // r=8191 pad does not exist
        bh[e] = (_Float16)w;
      }
#pragma unroll
      for (int fm = 0; fm < 2; ++fm)
        acc[fm][fj] = __builtin_amdgcn_mfma_f32_16x16x32_f16(a[fm], bh, acc[fm][fj], 0, 0, 0);
    }
  }
}

// ---- stage 2: fused even+odd chirp GEMM, full K, single plain store ----
__global__ __launch_bounds__(256) void s2_full(const float* __restrict__ x,
                                               const _Float16* __restrict__ xiT,
                                               const float* __restrict__ order,
                                               float* __restrict__ out) {
  int bx, by; swz_bxby(blockIdx.x, bx, by);
  const int lane = threadIdx.x & 63, wave = threadIdx.x >> 6;
  const int l15 = lane & 15, lhi = lane >> 4;
  const int b0 = by * 64 + (wave >> 1) * 32;
  const int j0 = bx * 64 + (wave & 1) * 32;
  const LitConsts L = get_lit(order);

  int jl[2]; float jbase[2];
#pragma unroll
  for (int fj = 0; fj < 2; ++fj) {
    jl[fj] = j0 + fj * 16 + l15;
    const int n = 2 * jl[fj] - (NN - 1);
    jbase[fj] = fmaf(-L.q, (float)(n * n), L.pe);
  }

  f32x4 acc[2][2] = {};  // [fm(b)][fj(j)]
  s2_seg<0>(x, xiT, L, jbase, jl, b0, l15, lhi, acc);
  s2_seg<1>(x, xiT, L, jbase, jl, b0, l15, lhi, acc);

#pragma unroll
  for (int fm = 0; fm < 2; ++fm) {
    const int br = b0 + fm * 16 + lhi * 4;
#pragma unroll
    for (int fj = 0; fj < 2; ++fj) {
#pragma unroll
      for (int rr = 0; rr < 4; ++rr)
        out[(size_t)(br + rr) * NN + jl[fj]] = L.scale * acc[fm][fj][rr];
    }
  }
}

// ======================= R13 proven fallback (small ws) =======================

__global__ __launch_bounds__(256) void frft_interp(const float* __restrict__ x,
                                                   __half* __restrict__ xi,
                                                   int b_lo, int cnt,
                                                   uint xi_cap, uint x_cap) {
  __shared__ __align__(16) float wt1[32][64];
  __shared__ __align__(16) float xt[32][64];
  const int tid = threadIdx.x;
  const int s0 = blockIdx.x * 64, cb0 = blockIdx.y * 64;
  const int tx = tid & 15, ty = tid >> 4;
  const int ss0 = ty * 4, bb0 = tx * 4;

  float acc[4][4] = {};
  for (int i0 = 0; i0 < NN; i0 += 32) {
#pragma unroll
    for (int e = 0; e < 8; ++e) {
      int idx = tid + e * 256, qq = idx >> 6, ss = idx & 63;
      int t = s0 + ss - (i0 + qq);
      float sgn = (t & 1) ? -0.63661977236758134f : 0.63661977236758134f;
      wt1[qq][ss] = __fdividef(sgn, (float)(2 * t + 1));
    }
#pragma unroll
    for (int e = 0; e < 8; ++e) {
      int idx = tid + e * 256, qq = idx >> 6, bb = idx & 63;
      xt[qq][bb] = xload(x, (uint)(b_lo + cb0 + bb) * NN + (i0 + qq), x_cap);
    }
    __syncthreads();
#pragma unroll
    for (int qq = 0; qq < 32; ++qq) {
      float4 wv = *(const float4*)&wt1[qq][ss0];
      float4 uv = *(const float4*)&xt[qq][bb0];
      float w[4] = {wv.x, wv.y, wv.z, wv.w};
      float u[4] = {uv.x, uv.y, uv.z, uv.w};
#pragma unroll
      for (int aa = 0; aa < 4; ++aa)
#pragma unroll
        for (int cc = 0; cc < 4; ++cc) acc[aa][cc] = fmaf(w[aa], u[cc], acc[aa][cc]);
    }
    __syncthreads();
  }
#pragma unroll
  for (int aa = 0; aa < 4; ++aa) {
    int s = s0 + ss0 + aa;
    if (s < NN - 1) {
#pragma unroll
      for (int cc = 0; cc < 4; ++cc) {
        int cb = cb0 + bb0 + cc;
        if (cb < cnt) {
          uint o = (uint)s * (uint)cnt + (uint)cb;
          if (o < xi_cap) xi[o] = __float2half(acc[aa][cc]);
        }
      }
    }
  }
}

#define TJ 32
#define TB 64
#define TK 32
__global__ __launch_bounds__(256) void frft_gemm(const float* __restrict__ x,
                                                 const __half* __restrict__ xi,
                                                 const float* __restrict__ order,
                                                 float* __restrict__ out,
                                                 int b_lo, int cnt,
                                                 uint xi_cap, uint x_cap,
                                                 uint out_capf) {
  __shared__ __align__(16) float wt[TK][TJ];
  __shared__ __align__(16) float ut[TK][TB];
  const int tid = threadIdx.x;
  const int j0 = blockIdx.x * TJ, cb0 = blockIdx.y * TB;
  const int tx = tid & 15, ty = tid >> 4;
  const int jj0 = ty * 2, bb0 = tx * 4;

  LitConsts L = get_lit(order);
  float acc[2][4] = {};

  for (int r0 = 0; r0 < KK; r0 += TK) {
#pragma unroll
    for (int e = 0; e < 4; ++e) {
      int idx = tid + e * 256, qq = idx >> 5, jj = idx & 31;
      int r = r0 + qq;
      float wv = 0.f;
      if (r < KK) {
        int j = j0 + jj;
        int n = 2 * j - (NN - 1);
        int d = 2 * j - r;
        int k = r - (NN - 1);
        float base = fmaf(-L.q, (float)(n * n), L.pe);
        float ph = fmaf(L.c, (float)(d * d), fmaf(-L.q, (float)(k * k), base));
        wv = __cosf(ph);
      }
      wt[qq][jj] = wv;
    }
#pragma unroll
    for (int e = 0; e < 8; ++e) {
      int idx = tid + e * 256, qq = idx >> 6, bb = idx & 63;
      int r = r0 + qq, cb = cb0 + bb;
      float v = 0.f;
      if (r < KK && cb < cnt) {
        if (r & 1) {
          uint o = (uint)(r >> 1) * (uint)cnt + (uint)cb;
          v = (o < xi_cap) ? __half2float(xi[o]) : 0.f;
        } else {
          v = xload(x, (uint)(b_lo + cb) * NN + (uint)(r >> 1), x_cap);
        }
      }
      ut[qq][bb] = v;
    }
    __syncthreads();
#pragma unroll
    for (int qq = 0; qq < TK; ++qq) {
      float2 wv = *(const float2*)&wt[qq][jj0];
      float4 uv = *(const float4*)&ut[qq][bb0];
      float w[2] = {wv.x, wv.y};
      float u[4] = {uv.x, uv.y, uv.z, uv.w};
#pragma unroll
      for (int aa = 0; aa < 2; ++aa)
#pragma unroll
        for (int cc = 0; cc < 4; ++cc)
          acc[aa][cc] = fmaf(w[aa], u[cc], acc[aa][cc]);
    }
    __syncthreads();
  }

#pragma unroll
  for (int aa = 0; aa < 2; ++aa) {
    int j = j0 + jj0 + aa;
#pragma unroll
    for (int cc = 0; cc < 4; ++cc) {
      int cb = cb0 + bb0 + cc;
      if (cb < cnt) {
        uint idx = (uint)(b_lo + cb) * NN + (uint)j;
        if (idx < out_capf) out[idx] = L.scale * acc[aa][cc];
      }
    }
  }
}

__global__ __launch_bounds__(256) void frft_gemm1(const float* __restrict__ x,
                                                  const float* __restrict__ order,
                                                  float* __restrict__ out,
                                                  uint x_cap, uint out_capf) {
  __shared__ float xrow[NN];
  __shared__ float xio[NN - 1];
  __shared__ float red[4][64];
  const int tid = threadIdx.x;
  const int j0 = blockIdx.x * 64;
  LitConsts L = get_lit(order);

#pragma unroll
  for (int e = 0; e < 16; ++e) {
    int i = tid + e * 256;
    xrow[i] = xload(x, (uint)255 * NN + (uint)i, x_cap);
  }
  __syncthreads();
#pragma unroll
  for (int m = 0; m < 16; ++m) {
    int s = tid + m * 256;
    if (s < NN - 1) {
      float a0 = 0.f;
      for (int i = 0; i < NN; ++i) {
        int t = s - i;
        float sgn = (t & 1) ? -0.63661977236758134f : 0.63661977236758134f;
        a0 = fmaf(xrow[i], __fdividef(sgn, (float)(2 * t + 1)), a0);
      }
      xio[s] = a0;
    }
  }
  __syncthreads();

  const int ty = tid >> 6, jj = tid & 63;
  const int j = j0 + jj;
  const int n = 2 * j - (NN - 1);
  const float base = fmaf(-L.q, (float)(n * n), L.pe);
  float acc = 0.f;
  int rend = (ty + 1) * 2048; if (rend > KK) rend = KK;
  for (int r = ty * 2048; r < rend; ++r) {
    int d = 2 * j - r;
    int k = r - (NN - 1);
    float ph = fmaf(L.c, (float)(d * d), fmaf(-L.q, (float)(k * k), base));
    float u = (r & 1) ? xio[r >> 1] : xrow[r >> 1];
    acc = fmaf(__cosf(ph), u, acc);
  }
  red[ty][jj] = acc;
  __syncthreads();
  if (ty == 0) {
    float t = red[0][jj] + red[1][jj] + red[2][jj] + red[3][jj];
    uint idx = (uint)255 * NN + (uint)j;
    if (idx < out_capf) out[idx] = L.scale * t;
  }
}

extern "C" void kernel_launch(void* const* d_in, const int* in_sizes, int n_in,
                              void* d_out, int out_size, void* d_ws, size_t ws_size,
                              hipStream_t stream) {
  const float* x     = (const float*)d_in[0];
  const float* order = (const float*)d_in[1];
  float* outf = (float*)d_out;
  const uint x_cap    = (uint)in_sizes[0];
  const uint out_capf = (uint)out_size;
  const size_t ws_halves = ws_size / 2;

  // ---- R15 full-K MFMA path: 2 kernels, zero atomics ----
  if (ws_size >= (size_t)NN * BB * 2 &&
      out_capf >= (uint)NN * BB && x_cap >= (uint)NN * BB) {
    _Float16* xiT = (_Float16*)d_ws;
    s1_full<<<dim3(256), 256, 0, stream>>>(x, xiT);
    s2_full<<<dim3(256), 256, 0, stream>>>(x, xiT, order, outf);
    return;
  }

  // ---- R13 proven fallback paths ----
  if (ws_halves >= (size_t)(NN - 1) * BB) {
    uint xi_cap = (uint)((size_t)(NN - 1) * BB);
    frft_interp<<<dim3(64, 4), 256, 0, stream>>>(x, (__half*)d_ws, 0, BB, xi_cap, x_cap);
    frft_gemm<<<dim3(NN / TJ, BB / TB), 256, 0, stream>>>(x, (__half*)d_ws, order, outf,
                                                          0, BB, xi_cap, x_cap, out_capf);
  } else {
    struct Chunk { int lo, cnt; };
    const Chunk ch[6] = { {0,170}, {170,57}, {227,19}, {246,6}, {252,2}, {254,1} };
    for (int i = 0; i < 6; ++i) {
      const Chunk& c = ch[i];
      uint off = (uint)(c.lo + c.cnt) * (uint)NN;
      __half* xp = (__half*)(outf + off);
      size_t need = (size_t)(NN - 1) * (size_t)c.cnt;
      size_t avail = (out_capf > off) ? (size_t)(out_capf - off) * 2 : 0;
      uint xi_cap = (uint)(need < avail ? need : avail);
      frft_interp<<<dim3(64, (unsigned)((c.cnt + 63) / 64)), 256, 0, stream>>>(
          x, xp, c.lo, c.cnt, xi_cap, x_cap);
      frft_gemm<<<dim3(NN / TJ, (unsigned)((c.cnt + TB - 1) / TB)), 256, 0, stream>>>(
          x, xp, order, outf, c.lo, c.cnt, xi_cap, x_cap, out_capf);
    }
    if (ws_halves >= (size_t)(NN - 1)) {
      uint xi_cap = (uint)(NN - 1);
      frft_interp<<<dim3(64, 1), 256, 0, stream>>>(x, (__half*)d_ws, 255, 1, xi_cap, x_cap);
      frft_gemm<<<dim3(NN / TJ, 1), 256, 0, stream>>>(x, (__half*)d_ws, order, outf,
                                                      255, 1, xi_cap, x_cap, out_capf);
    } else {
      frft_gemm1<<<64, 256, 0, stream>>>(x, order, outf, x_cap, out_capf);
    }
  }
}